// Round 1
// baseline (54786.987 us; speedup 1.0000x reference)
//
#include <hip/hip_runtime.h>
#include <cmath>

// RSSM scan: B=16, T=64, A=6, E=12288, DET=4096, HID=1024, S=32, D=32
// fp32 throughout (argmax stability requires it). Deterministic reductions.

#define B 16
#define T_STEPS 64
#define A_DIM 6
#define E_DIM 12288
#define DET 4096
#define HID 1024
#define SD 1024          // S*D
#define OUT_C 8192       // per (b,t) output row
#define OUT_RSTRIDE (T_STEPS * OUT_C)  // 524288, row stride over b in d_out

// ---------------- block reduce (deterministic) ----------------
__device__ __forceinline__ float block_sum(float v, float* red, int nw) {
#pragma unroll
  for (int m = 32; m >= 1; m >>= 1) v += __shfl_xor(v, m, 64);
  int wid = threadIdx.x >> 6;
  if ((threadIdx.x & 63) == 0) red[wid] = v;
  __syncthreads();
  if (wid == 0) {
    float s = ((int)threadIdx.x < nw) ? red[threadIdx.x] : 0.0f;
#pragma unroll
    for (int m = 8; m >= 1; m >>= 1) s += __shfl_xor(s, m, 16);
    if (threadIdx.x == 0) red[0] = s;
  }
  __syncthreads();
  float out = red[0];
  __syncthreads();
  return out;
}

// ---------------- init: init_deter = tanh(w_init) ----------------
__global__ __launch_bounds__(1024) void k_tanh(const float* __restrict__ w, float* __restrict__ o) {
  int i = blockIdx.x * 1024 + threadIdx.x;
  if (i < DET) o[i] = tanhf(w[i]);
}

// ---------------- prep: resets + action clip ----------------
__global__ __launch_bounds__(256) void k_prep(
    const float* __restrict__ isf, const float* __restrict__ pa, int t,
    const float* __restrict__ stoch_prev,
    const float* __restrict__ deter_prev, long deter_prev_stride,
    const float* __restrict__ init_stoch, const float* __restrict__ init_deter_row,
    float* __restrict__ stoch_in, float* __restrict__ deter_in, float* __restrict__ a_eff) {
  int r = blockIdx.x;
  float f = isf[r * T_STEPS + t];
  float omf = 1.0f - f;
  for (int c = threadIdx.x; c < SD; c += 256)
    stoch_in[r * SD + c] = stoch_prev[r * SD + c] * omf + init_stoch[r * SD + c] * f;
  for (int c = threadIdx.x; c < DET; c += 256)
    deter_in[r * DET + c] = deter_prev[(long)r * deter_prev_stride + c] * omf + init_deter_row[c] * f;
  if ((int)threadIdx.x < A_DIM) {
    float a = pa[(r * T_STEPS + t) * A_DIM + threadIdx.x];
    a = a * (1.0f / fmaxf(fabsf(a), 1.0f));   // clip_act
    a_eff[r * 8 + threadIdx.x] = a * omf;     // second clip is exact identity on |a|<=1
  }
}

// ---------------- img1: x = silu(LN(concat(stoch,a) @ W1)) fused ----------------
__global__ __launch_bounds__(1024) void k_img1(
    const float* __restrict__ stoch_in, const float* __restrict__ a_eff,
    const float* __restrict__ W, const float* __restrict__ g, const float* __restrict__ b,
    float* __restrict__ xout) {
  int r = blockIdx.x, c = threadIdx.x;
  __shared__ float in_s[SD + A_DIM];
  __shared__ float red[18];
  in_s[c] = stoch_in[r * SD + c];
  if (c < A_DIM) in_s[SD + c] = a_eff[r * 8 + c];
  __syncthreads();
  float acc = 0.0f;
#pragma unroll 10
  for (int k = 0; k < SD + A_DIM; k++) acc += in_s[k] * W[(size_t)k * HID + c];
  float m = block_sum(acc, red, 16) * (1.0f / (float)HID);
  float d = acc - m;
  float var = block_sum(d * d, red, 16) * (1.0f / (float)HID);
  float rs = 1.0f / sqrtf(var + 1e-3f);
  float y = d * rs * g[c] + b[c];
  float s = 1.0f / (1.0f + expf(-y));
  xout[r * HID + c] = y * s;
}

// ---------------- generic K-split GEMM partial: out[ksplit][16][N] ----------------
// block: 256 thr, 1024 cols (4/thread), 16 rows; grid (N/1024, K/KS)
__global__ __launch_bounds__(256) void k_gemm(
    const float* __restrict__ A0, long sA0, int cA0,
    const float* __restrict__ A1, long sA1,
    const float* __restrict__ W, int N, int KS,
    float* __restrict__ P) {
  const int tid = threadIdx.x;
  const int c0 = blockIdx.x * 1024 + tid * 4;
  const long k0 = (long)blockIdx.y * KS;
  __shared__ float in_s[16][64];
  float acc[16][4];
#pragma unroll
  for (int r = 0; r < 16; r++) { acc[r][0] = 0; acc[r][1] = 0; acc[r][2] = 0; acc[r][3] = 0; }
  for (int kb = 0; kb < KS; kb += 64) {
    const long kbase = k0 + kb;
#pragma unroll
    for (int j = 0; j < 4; j++) {
      int idx = tid + j * 256;
      int r = idx >> 6, kk = idx & 63;
      long k = kbase + kk;
      float v = (k < cA0) ? A0[r * sA0 + k] : A1[r * sA1 + (k - cA0)];
      in_s[r][kk] = v;
    }
    __syncthreads();
#pragma unroll 4
    for (int kk = 0; kk < 64; kk++) {
      const float* wp = W + (size_t)(kbase + kk) * N + c0;
      float w0 = wp[0], w1 = wp[1], w2 = wp[2], w3 = wp[3];
#pragma unroll
      for (int r = 0; r < 16; r++) {
        float iv = in_s[r][kk];
        acc[r][0] += iv * w0; acc[r][1] += iv * w1; acc[r][2] += iv * w2; acc[r][3] += iv * w3;
      }
    }
    __syncthreads();
  }
#pragma unroll
  for (int r = 0; r < 16; r++) {
    float* op = P + ((size_t)(blockIdx.y * 16 + r)) * N + c0;
    op[0] = acc[r][0]; op[1] = acc[r][1]; op[2] = acc[r][2]; op[3] = acc[r][3];
  }
}

// ---------------- GRU finish: sum partials, LN(12288), gates, deter_new ----------------
__global__ __launch_bounds__(256) void k_gru_fin(
    const float* __restrict__ P, int nP,
    const float* __restrict__ g, const float* __restrict__ b,
    const float* __restrict__ deter_in, float* __restrict__ deter_new,
    float* __restrict__ out_deter) {
  int r = blockIdx.x;
  __shared__ float ps[3 * DET];
  __shared__ float red[18];
  float lsum = 0.0f;
  for (int c = threadIdx.x; c < 3 * DET; c += 256) {
    float v = 0.0f;
    for (int ks = 0; ks < nP; ks++) v += P[((size_t)ks * 16 + r) * (3 * DET) + c];
    ps[c] = v; lsum += v;
  }
  float m = block_sum(lsum, red, 4) * (1.0f / (float)(3 * DET));
  float lv = 0.0f;
  for (int c = threadIdx.x; c < 3 * DET; c += 256) { float d = ps[c] - m; lv += d * d; }
  float var = block_sum(lv, red, 4) * (1.0f / (float)(3 * DET));
  float rs = 1.0f / sqrtf(var + 1e-3f);
  for (int j = threadIdx.x; j < DET; j += 256) {
    float lr = (ps[j] - m) * rs * g[j] + b[j];
    float lc = (ps[j + DET] - m) * rs * g[j + DET] + b[j + DET];
    float lu = (ps[j + 2 * DET] - m) * rs * g[j + 2 * DET] + b[j + 2 * DET];
    float rr = 1.0f / (1.0f + expf(-lr));
    float cd = tanhf(rr * lc);
    float uu = 1.0f / (1.0f + expf(-(lu - 1.0f)));
    float dn = uu * cd + (1.0f - uu) * deter_in[r * DET + j];
    deter_new[r * DET + j] = dn;
    out_deter[(size_t)r * OUT_RSTRIDE + j] = dn;
  }
}

// ---------------- finish: sum partials, LN(1024), silu ----------------
__global__ __launch_bounds__(256) void k_fin_ln_silu(
    const float* __restrict__ P, int nP,
    const float* __restrict__ g, const float* __restrict__ b,
    float* __restrict__ out) {
  int r = blockIdx.x;
  __shared__ float ps[HID];
  __shared__ float red[18];
  float lsum = 0.0f;
  for (int c = threadIdx.x; c < HID; c += 256) {
    float v = 0.0f;
    for (int ks = 0; ks < nP; ks++) v += P[((size_t)ks * 16 + r) * HID + c];
    ps[c] = v; lsum += v;
  }
  float m = block_sum(lsum, red, 4) * (1.0f / (float)HID);
  float lv = 0.0f;
  for (int c = threadIdx.x; c < HID; c += 256) { float d = ps[c] - m; lv += d * d; }
  float var = block_sum(lv, red, 4) * (1.0f / (float)HID);
  float rs = 1.0f / sqrtf(var + 1e-3f);
  for (int c = threadIdx.x; c < HID; c += 256) {
    float y = (ps[c] - m) * rs * g[c] + b[c];
    float s = 1.0f / (1.0f + expf(-y));
    out[r * HID + c] = y * s;
  }
}

// ---------------- sample: logits = h @ W + bb; mix-softmax; ST gumbel/mode ----------------
__global__ __launch_bounds__(1024) void k_sample(
    const float* __restrict__ h, const float* __restrict__ W, const float* __restrict__ bb,
    const float* __restrict__ gum, long gstride,
    float* __restrict__ out_stoch, long ss,
    float* __restrict__ out_logits, long ls,
    float* __restrict__ carry) {
  int r = blockIdx.x, c = threadIdx.x;
  int d = c & 31;
  __shared__ float h_s[HID];
  h_s[c] = h[r * HID + c];
  __syncthreads();
  float acc = bb[c];
#pragma unroll 8
  for (int k = 0; k < HID; k++) acc += h_s[k] * W[(size_t)k * SD + c];
  float lg = acc;
  // softmax over group of 32 lanes (aligned: width=32)
  float mx = lg;
#pragma unroll
  for (int m = 16; m >= 1; m >>= 1) mx = fmaxf(mx, __shfl_xor(mx, m, 32));
  float e = expf(lg - mx);
  float se = e;
#pragma unroll
  for (int m = 16; m >= 1; m >>= 1) se += __shfl_xor(se, m, 32);
  float p = 0.99f * (e / se) + 3.125e-4f;   // (1-UM)*softmax + UM/D
  float y = gum ? (logf(p) + gum[(long)r * gstride + c]) : p;
  // argmax, first-occurrence tie-break (matches np.argmax)
  float by = y; int bi = d;
#pragma unroll
  for (int m = 16; m >= 1; m >>= 1) {
    float oy = __shfl_xor(by, m, 32);
    int oi = __shfl_xor(bi, m, 32);
    if (oy > by || (oy == by && oi < bi)) { by = oy; bi = oi; }
  }
  float oh = (d == bi) ? 1.0f : 0.0f;
  float outv = (oh + p) - p;   // same op order as reference forward
  out_stoch[(long)r * ss + c] = outv;
  if (out_logits) out_logits[(long)r * ls + c] = lg;
  if (carry) carry[r * SD + c] = outv;
}

// ---------------- host ----------------
extern "C" void kernel_launch(void* const* d_in, const int* in_sizes, int n_in,
                              void* d_out, int out_size, void* d_ws, size_t ws_size,
                              hipStream_t stream) {
  const float* embed  = (const float*)d_in[0];
  const float* pa     = (const float*)d_in[1];
  const float* isf    = (const float*)d_in[2];
  const float* gprior = (const float*)d_in[3];
  const float* gpost  = (const float*)d_in[4];
  const float* w_init = (const float*)d_in[5];
  const float* W1  = (const float*)d_in[6];
  const float* g1  = (const float*)d_in[7];
  const float* b1  = (const float*)d_in[8];
  const float* Wg  = (const float*)d_in[9];
  const float* gg  = (const float*)d_in[10];
  const float* bg  = (const float*)d_in[11];
  const float* W2a = (const float*)d_in[12];
  const float* g2  = (const float*)d_in[13];
  const float* b2  = (const float*)d_in[14];
  const float* W2b = (const float*)d_in[15];
  const float* bb2 = (const float*)d_in[16];
  const float* Wo  = (const float*)d_in[17];
  const float* go  = (const float*)d_in[18];
  const float* bo  = (const float*)d_in[19];
  const float* Wob = (const float*)d_in[20];
  const float* bbo = (const float*)d_in[21];
  float* out = (float*)d_out;
  float* ws  = (float*)d_ws;

  // workspace layout (floats)
  float* P          = ws;                       // max 20*16*12288 = 3,932,160
  float* init_stoch = P + 3932160;              // 16*1024
  float* init_deter = init_stoch + 16384;       // 4096 (one row, broadcast)
  float* stoch_carry= init_deter + 4096;        // 16*1024
  float* stoch_in   = stoch_carry + 16384;      // 16*1024
  float* deter_in   = stoch_in + 16384;         // 16*4096
  float* deter_new  = deter_in + 65536;         // 16*4096
  float* a_eff      = deter_new + 65536;        // 16*8
  float* x          = a_eff + 128;              // 16*1024
  float* h          = x + 16384;                // 16*1024
  float* h2         = h + 16384;                // 16*1024

  // ---- init: init_deter = tanh(w_init); init_stoch = st_mode(prior_logits(init_deter))
  k_tanh<<<4, 1024, 0, stream>>>(w_init, init_deter);
  k_gemm<<<dim3(1, 32), 256, 0, stream>>>(init_deter, 0, DET, nullptr, 0, W2a, HID, 128, P);
  k_fin_ln_silu<<<16, 256, 0, stream>>>(P, 32, g2, b2, h);
  k_sample<<<16, 1024, 0, stream>>>(h, W2b, bb2, nullptr, 0, init_stoch, SD, nullptr, 0, nullptr);

  for (int t = 0; t < T_STEPS; t++) {
    k_prep<<<16, 256, 0, stream>>>(isf, pa, t,
                                   t == 0 ? init_stoch : stoch_carry,
                                   t == 0 ? init_deter : deter_new,
                                   t == 0 ? 0 : (long)DET,
                                   init_stoch, init_deter, stoch_in, deter_in, a_eff);
    k_img1<<<16, 1024, 0, stream>>>(stoch_in, a_eff, W1, g1, b1, x);
    // GRU: concat(x[1024], deter_in[4096]) @ Wg (5120 x 12288), KSPLIT=20, KS=256
    k_gemm<<<dim3(12, 20), 256, 0, stream>>>(x, HID, HID, deter_in, DET, Wg, 3 * DET, 256, P);
    k_gru_fin<<<16, 256, 0, stream>>>(P, 20, gg, bg, deter_in, deter_new,
                                      out + (size_t)t * OUT_C + 1024);
    // prior: img2a (4096 -> 1024), KSPLIT=32, KS=128
    k_gemm<<<dim3(1, 32), 256, 0, stream>>>(deter_new, DET, DET, nullptr, 0, W2a, HID, 128, P);
    k_fin_ln_silu<<<16, 256, 0, stream>>>(P, 32, g2, b2, h);
    k_sample<<<16, 1024, 0, stream>>>(h, W2b, bb2,
                                      gprior + (size_t)t * SD, (long)T_STEPS * SD,
                                      out + (size_t)t * OUT_C + 6144, OUT_RSTRIDE,
                                      out + (size_t)t * OUT_C + 7168, OUT_RSTRIDE,
                                      nullptr);
    // obs: concat(e[12288], deter_new[4096]) @ Wo (16384 x 1024), KSPLIT=128, KS=128
    k_gemm<<<dim3(1, 128), 256, 0, stream>>>(embed + (size_t)t * E_DIM, (long)T_STEPS * E_DIM,
                                             E_DIM, deter_new, DET, Wo, HID, 128, P);
    k_fin_ln_silu<<<16, 256, 0, stream>>>(P, 128, go, bo, h2);
    k_sample<<<16, 1024, 0, stream>>>(h2, Wob, bbo,
                                      gpost + (size_t)t * SD, (long)T_STEPS * SD,
                                      out + (size_t)t * OUT_C + 0, OUT_RSTRIDE,
                                      out + (size_t)t * OUT_C + 5120, OUT_RSTRIDE,
                                      stoch_carry);
  }
}

// Round 2
// 16440.376 us; speedup vs baseline: 3.3325x; 3.3325x over previous
//
#include <hip/hip_runtime.h>
#include <cmath>

// RSSM scan: B=16, T=64, A=6, E=12288, DET=4096, HID=1024, S=32, D=32
// fp32 throughout (argmax stability). Deterministic reductions.

#define B 16
#define T_STEPS 64
#define A_DIM 6
#define E_DIM 12288
#define DET 4096
#define HID 1024
#define SD 1024
#define OUT_C 8192
#define OUT_RSTRIDE (T_STEPS * OUT_C)

// ---------------- block reduce (deterministic) ----------------
__device__ __forceinline__ float block_sum(float v, float* red, int nw) {
#pragma unroll
  for (int m = 32; m >= 1; m >>= 1) v += __shfl_xor(v, m, 64);
  int wid = threadIdx.x >> 6;
  if ((threadIdx.x & 63) == 0) red[wid] = v;
  __syncthreads();
  if (wid == 0) {
    float s = ((int)threadIdx.x < nw) ? red[threadIdx.x] : 0.0f;
#pragma unroll
    for (int m = 8; m >= 1; m >>= 1) s += __shfl_xor(s, m, 16);
    if (threadIdx.x == 0) red[0] = s;
  }
  __syncthreads();
  float out = red[0];
  __syncthreads();
  return out;
}

__global__ __launch_bounds__(1024) void k_tanh(const float* __restrict__ w, float* __restrict__ o) {
  int i = blockIdx.x * 1024 + threadIdx.x;
  if (i < DET) o[i] = tanhf(w[i]);
}

// ---------------- prep: resets + action clip ----------------
__global__ __launch_bounds__(256) void k_prep(
    const float* __restrict__ isf, const float* __restrict__ pa, int t,
    const float* __restrict__ stoch_prev,
    const float* __restrict__ deter_prev, long deter_prev_stride,
    const float* __restrict__ init_stoch, const float* __restrict__ init_deter_row,
    float* __restrict__ stoch_in, float* __restrict__ deter_in, float* __restrict__ a_eff) {
  int r = blockIdx.x;
  float f = isf[r * T_STEPS + t];
  float omf = 1.0f - f;
  for (int c = threadIdx.x; c < SD; c += 256)
    stoch_in[r * SD + c] = stoch_prev[r * SD + c] * omf + init_stoch[r * SD + c] * f;
  for (int c = threadIdx.x; c < DET; c += 256)
    deter_in[r * DET + c] = deter_prev[(long)r * deter_prev_stride + c] * omf + init_deter_row[c] * f;
  if ((int)threadIdx.x < A_DIM) {
    float a = pa[(r * T_STEPS + t) * A_DIM + threadIdx.x];
    a = a * (1.0f / fmaxf(fabsf(a), 1.0f));
    a_eff[r * 8 + threadIdx.x] = a * omf;
  }
}

// ---------------- generic K-split GEMM: P[split][16][N] partials ----------------
// 256 threads, 512 cols/block (float2), 16 rows staged in LDS.
// Batched: blockIdx.z selects ga/gb.
struct GemmArgs {
  const float* A0; long sA0; int cA0;   // k < cA0 -> A0[r*sA0 + k]
  const float* A1; long sA1;            // cA0 <= k < Ktot -> A1[r*sA1 + (k-cA0)]
  const float* W; int N; int Ktot; int KS; int nsplit;
  float* P;
};

__global__ __launch_bounds__(256) void k_gemm(GemmArgs ga, GemmArgs gb) {
  const GemmArgs g = blockIdx.z ? gb : ga;
  if ((int)blockIdx.y >= g.nsplit) return;
  const int tid = threadIdx.x;
  const int c0 = blockIdx.x * 512 + tid * 2;
  const int k0 = (int)blockIdx.y * g.KS;
  __shared__ float in_s[16][64];
  float acc[16][2];
#pragma unroll
  for (int r = 0; r < 16; r++) { acc[r][0] = 0.f; acc[r][1] = 0.f; }
  for (int kb = 0; kb < g.KS; kb += 64) {
    const int kbase = k0 + kb;
#pragma unroll
    for (int j = 0; j < 4; j++) {
      int ii = tid + j * 256;
      int r = ii >> 6, kk = ii & 63;
      int k = kbase + kk;
      float v = 0.f;
      if (k < g.cA0) v = g.A0[(long)r * g.sA0 + k];
      else if (k < g.Ktot) v = g.A1[(long)r * g.sA1 + (k - g.cA0)];
      in_s[r][kk] = v;
    }
    __syncthreads();
    if (kbase + 64 <= g.Ktot) {  // fast affine path
      const float* wp = g.W + (size_t)kbase * g.N + c0;
#pragma unroll 4
      for (int kk = 0; kk < 64; kk++) {
        const float2 w = *(const float2*)wp; wp += g.N;
#pragma unroll
        for (int r = 0; r < 16; r++) {
          float iv = in_s[r][kk];
          acc[r][0] += iv * w.x; acc[r][1] += iv * w.y;
        }
      }
    } else {  // K tail (img1: Ktot=1030): clamp row, staged zeros kill contribution
#pragma unroll 4
      for (int kk = 0; kk < 64; kk++) {
        int krow = kbase + kk; if (krow >= g.Ktot) krow = g.Ktot - 1;
        const float2 w = *(const float2*)(g.W + (size_t)krow * g.N + c0);
#pragma unroll
        for (int r = 0; r < 16; r++) {
          float iv = in_s[r][kk];
          acc[r][0] += iv * w.x; acc[r][1] += iv * w.y;
        }
      }
    }
    __syncthreads();
  }
#pragma unroll
  for (int r = 0; r < 16; r++)
    *(float2*)(g.P + ((size_t)blockIdx.y * 16 + r) * g.N + c0) = make_float2(acc[r][0], acc[r][1]);
}

// ---------------- batched finish: sum partials + LN(1024) + silu ----------------
__global__ __launch_bounds__(1024) void k_fin2(
    const float* __restrict__ Pa, int nPa, const float* __restrict__ gva, const float* __restrict__ bva, float* __restrict__ oa,
    const float* __restrict__ Pb, int nPb, const float* __restrict__ gvb, const float* __restrict__ bvb, float* __restrict__ ob) {
  int which = blockIdx.x >> 4, r = blockIdx.x & 15, c = threadIdx.x;
  const float* P = which ? Pb : Pa;
  int nP = which ? nPb : nPa;
  const float* gv = which ? gvb : gva;
  const float* bv = which ? bvb : bva;
  float* o = which ? ob : oa;
  __shared__ float red[18];
  float v = 0.f;
  for (int ks = 0; ks < nP; ks++) v += P[((size_t)ks * 16 + r) * HID + c];
  float m = block_sum(v, red, 16) * (1.0f / (float)HID);
  float d = v - m;
  float var = block_sum(d * d, red, 16) * (1.0f / (float)HID);
  float rs = 1.0f / sqrtf(var + 1e-3f);
  float y = d * rs * gv[c] + bv[c];
  float s = 1.0f / (1.0f + expf(-y));
  o[r * HID + c] = y * s;
}

// ---------------- GRU finish: sum partials, LN(12288), gates ----------------
__global__ __launch_bounds__(1024) void k_gru_fin(
    const float* __restrict__ P, int nP,
    const float* __restrict__ g, const float* __restrict__ b,
    const float* __restrict__ deter_in, float* __restrict__ deter_new,
    float* __restrict__ out_deter) {
  int r = blockIdx.x;
  __shared__ float ps[3 * DET];
  __shared__ float red[18];
  float lsum = 0.0f;
  for (int c = threadIdx.x; c < 3 * DET; c += 1024) {
    float v = 0.0f;
    for (int ks = 0; ks < nP; ks++) v += P[((size_t)ks * 16 + r) * (3 * DET) + c];
    ps[c] = v; lsum += v;
  }
  float m = block_sum(lsum, red, 16) * (1.0f / (float)(3 * DET));
  float lv = 0.0f;
  for (int c = threadIdx.x; c < 3 * DET; c += 1024) { float d = ps[c] - m; lv += d * d; }
  float var = block_sum(lv, red, 16) * (1.0f / (float)(3 * DET));
  float rs = 1.0f / sqrtf(var + 1e-3f);
  for (int j = threadIdx.x; j < DET; j += 1024) {
    float lr = (ps[j] - m) * rs * g[j] + b[j];
    float lc = (ps[j + DET] - m) * rs * g[j + DET] + b[j + DET];
    float lu = (ps[j + 2 * DET] - m) * rs * g[j + 2 * DET] + b[j + 2 * DET];
    float rr = 1.0f / (1.0f + expf(-lr));
    float cd = tanhf(rr * lc);
    float uu = 1.0f / (1.0f + expf(-(lu - 1.0f)));
    float dn = uu * cd + (1.0f - uu) * deter_in[r * DET + j];
    deter_new[r * DET + j] = dn;
    out_deter[(size_t)r * OUT_RSTRIDE + j] = dn;
  }
}

// ---------------- batched sample finish: sum partials + bias, mix-softmax, ST ----------------
__global__ __launch_bounds__(1024) void k_samp(
    const float* __restrict__ P0, const float* __restrict__ bb0,
    const float* __restrict__ gum0, long gs0,
    float* __restrict__ st0, long ss0, float* __restrict__ lg0, long ls0,
    const float* __restrict__ P1, const float* __restrict__ bb1,
    const float* __restrict__ gum1, long gs1,
    float* __restrict__ st1, long ss1, float* __restrict__ lg1, long ls1,
    float* __restrict__ carry, int nP) {
  int which = blockIdx.x >> 4, r = blockIdx.x & 15, c = threadIdx.x;
  const float* P = which ? P1 : P0;
  const float* bbv = which ? bb1 : bb0;
  const float* gum = which ? gum1 : gum0;
  long gs = which ? gs1 : gs0;
  float* st = which ? st1 : st0;
  long ss = which ? ss1 : ss0;
  float* lg = which ? lg1 : lg0;
  long ls = which ? ls1 : ls0;
  float acc = bbv[c];
  for (int ks = 0; ks < nP; ks++) acc += P[((size_t)ks * 16 + r) * SD + c];
  int d = c & 31;
  float mx = acc;
#pragma unroll
  for (int m = 16; m >= 1; m >>= 1) mx = fmaxf(mx, __shfl_xor(mx, m, 32));
  float e = expf(acc - mx);
  float se = e;
#pragma unroll
  for (int m = 16; m >= 1; m >>= 1) se += __shfl_xor(se, m, 32);
  float p = 0.99f * (e / se) + 3.125e-4f;
  float y = gum ? (logf(p) + gum[(long)r * gs + c]) : p;
  float by = y; int bi = d;
#pragma unroll
  for (int m = 16; m >= 1; m >>= 1) {
    float oy = __shfl_xor(by, m, 32);
    int oi = __shfl_xor(bi, m, 32);
    if (oy > by || (oy == by && oi < bi)) { by = oy; bi = oi; }
  }
  float oh = (d == bi) ? 1.0f : 0.0f;
  float outv = (oh + p) - p;
  st[(long)r * ss + c] = outv;
  if (lg) lg[(long)r * ls + c] = acc;
  if (which && carry) carry[r * SD + c] = outv;
}

// ---------------- host ----------------
static inline GemmArgs mkargs(const float* A0, long sA0, int cA0,
                              const float* A1, long sA1,
                              const float* W, int N, int Ktot, int KS, int nsplit, float* P) {
  GemmArgs g; g.A0 = A0; g.sA0 = sA0; g.cA0 = cA0; g.A1 = A1; g.sA1 = sA1;
  g.W = W; g.N = N; g.Ktot = Ktot; g.KS = KS; g.nsplit = nsplit; g.P = P;
  return g;
}

extern "C" void kernel_launch(void* const* d_in, const int* in_sizes, int n_in,
                              void* d_out, int out_size, void* d_ws, size_t ws_size,
                              hipStream_t stream) {
  const float* embed  = (const float*)d_in[0];
  const float* pa     = (const float*)d_in[1];
  const float* isf    = (const float*)d_in[2];
  const float* gprior = (const float*)d_in[3];
  const float* gpost  = (const float*)d_in[4];
  const float* w_init = (const float*)d_in[5];
  const float* W1  = (const float*)d_in[6];
  const float* g1  = (const float*)d_in[7];
  const float* b1  = (const float*)d_in[8];
  const float* Wg  = (const float*)d_in[9];
  const float* gg  = (const float*)d_in[10];
  const float* bg  = (const float*)d_in[11];
  const float* W2a = (const float*)d_in[12];
  const float* g2  = (const float*)d_in[13];
  const float* b2  = (const float*)d_in[14];
  const float* W2b = (const float*)d_in[15];
  const float* bb2 = (const float*)d_in[16];
  const float* Wo  = (const float*)d_in[17];
  const float* go  = (const float*)d_in[18];
  const float* bo  = (const float*)d_in[19];
  const float* Wob = (const float*)d_in[20];
  const float* bbo = (const float*)d_in[21];
  float* out = (float*)d_out;
  float* ws  = (float*)d_ws;

  // workspace (floats). Partial region R reused across phases within a step.
  float* R = ws;
  float* Pimg1 = R;               // 17*16*1024  = 278,528
  float* Pg    = R;               // 20*16*12288 = 3,932,160
  float* Pa    = R;               // 64*16*1024  = 1,048,576
  float* Pb    = R + 1048576;     // 128*16*1024 = 2,097,152
  float* Ps0   = R + 3145728;     // 16*16*1024  = 262,144
  float* Ps1   = R + 3407872;     // 262,144
  float* st_   = R + 3932160;
  float* init_stoch = st_;            // 16384
  float* init_deter = st_ + 16384;    // 4096
  float* stoch_carry= st_ + 20480;    // 16384
  float* stoch_in   = st_ + 36864;    // 16384
  float* deter_in   = st_ + 53248;    // 65536
  float* deter_new  = st_ + 118784;   // 65536
  float* a_eff      = st_ + 184320;   // 128
  float* x          = st_ + 184448;   // 16384
  float* h          = st_ + 200832;   // 16384
  float* h2         = st_ + 217216;   // 16384

  GemmArgs Z = mkargs(nullptr, 0, 0, nullptr, 0, nullptr, 1, 0, 64, 0, nullptr);

  // ---- init: init_deter = tanh(w_init); init_stoch = st_mode(prior_logits(init_deter))
  k_tanh<<<4, 1024, 0, stream>>>(w_init, init_deter);
  {
    GemmArgs g = mkargs(init_deter, 0, DET, nullptr, 0, W2a, HID, DET, 64, 64, Pa);
    k_gemm<<<dim3(2, 64, 1), 256, 0, stream>>>(g, Z);
  }
  k_fin2<<<16, 1024, 0, stream>>>(Pa, 64, g2, b2, h, Pa, 64, g2, b2, h);
  {
    GemmArgs g = mkargs(h, HID, HID, nullptr, 0, W2b, SD, HID, 64, 16, Ps0);
    k_gemm<<<dim3(2, 16, 1), 256, 0, stream>>>(g, Z);
  }
  k_samp<<<16, 1024, 0, stream>>>(Ps0, bb2, nullptr, 0, init_stoch, SD, nullptr, 0,
                                  Ps0, bb2, nullptr, 0, init_stoch, SD, nullptr, 0,
                                  nullptr, 16);

  for (int t = 0; t < T_STEPS; t++) {
    k_prep<<<16, 256, 0, stream>>>(isf, pa, t,
                                   t == 0 ? init_stoch : stoch_carry,
                                   t == 0 ? init_deter : deter_new,
                                   t == 0 ? 0 : (long)DET,
                                   init_stoch, init_deter, stoch_in, deter_in, a_eff);
    {  // img1: concat(stoch,a)[1030] @ W1 -> 1024
      GemmArgs g = mkargs(stoch_in, SD, SD, a_eff, 8, W1, HID, SD + A_DIM, 64, 17, Pimg1);
      k_gemm<<<dim3(2, 17, 1), 256, 0, stream>>>(g, Z);
    }
    k_fin2<<<16, 1024, 0, stream>>>(Pimg1, 17, g1, b1, x, Pimg1, 17, g1, b1, x);
    {  // GRU: concat(x,deter_in)[5120] @ Wg -> 12288
      GemmArgs g = mkargs(x, HID, HID, deter_in, DET, Wg, 3 * DET, HID + DET, 256, 20, Pg);
      k_gemm<<<dim3(24, 20, 1), 256, 0, stream>>>(g, Z);
    }
    k_gru_fin<<<16, 1024, 0, stream>>>(Pg, 20, gg, bg, deter_in, deter_new,
                                       out + (size_t)t * OUT_C + 1024);
    {  // batched: prior img2a (4096->1024) || obs (16384->1024)
      GemmArgs ga = mkargs(deter_new, DET, DET, nullptr, 0, W2a, HID, DET, 64, 64, Pa);
      GemmArgs gb = mkargs(embed + (size_t)t * E_DIM, (long)T_STEPS * E_DIM, E_DIM,
                           deter_new, DET, Wo, HID, E_DIM + DET, 128, 128, Pb);
      k_gemm<<<dim3(2, 128, 2), 256, 0, stream>>>(ga, gb);
    }
    k_fin2<<<32, 1024, 0, stream>>>(Pa, 64, g2, b2, h, Pb, 128, go, bo, h2);
    {  // batched sample GEMMs: h@W2b || h2@Wob (1024->1024)
      GemmArgs ga = mkargs(h, HID, HID, nullptr, 0, W2b, SD, HID, 64, 16, Ps0);
      GemmArgs gb = mkargs(h2, HID, HID, nullptr, 0, Wob, SD, HID, 64, 16, Ps1);
      k_gemm<<<dim3(2, 16, 2), 256, 0, stream>>>(ga, gb);
    }
    k_samp<<<32, 1024, 0, stream>>>(
        Ps0, bb2, gprior + (size_t)t * SD, (long)T_STEPS * SD,
        out + (size_t)t * OUT_C + 6144, OUT_RSTRIDE,
        out + (size_t)t * OUT_C + 7168, OUT_RSTRIDE,
        Ps1, bbo, gpost + (size_t)t * SD, (long)T_STEPS * SD,
        out + (size_t)t * OUT_C + 0, OUT_RSTRIDE,
        out + (size_t)t * OUT_C + 5120, OUT_RSTRIDE,
        stoch_carry, 16);
  }
}

// Round 3
// 10939.125 us; speedup vs baseline: 5.0084x; 1.5029x over previous
//
#include <hip/hip_runtime.h>
#include <cmath>

// RSSM scan: B=16, T=64, A=6, E=12288, DET=4096, HID=1024, S=32, D=32
// fp32 throughout (argmax stability). Deterministic fixed-order reductions.

#define B 16
#define T_STEPS 64
#define A_DIM 6
#define E_DIM 12288
#define DET 4096
#define HID 1024
#define SD 1024
#define OUT_C 8192
#define OUT_RSTRIDE (T_STEPS * OUT_C)

typedef float f2v __attribute__((ext_vector_type(2)));

// ---------------- block reduce (deterministic) ----------------
__device__ __forceinline__ float block_sum(float v, float* red, int nw) {
#pragma unroll
  for (int m = 32; m >= 1; m >>= 1) v += __shfl_xor(v, m, 64);
  int wid = threadIdx.x >> 6;
  if ((threadIdx.x & 63) == 0) red[wid] = v;
  __syncthreads();
  if (wid == 0) {
    float s = ((int)threadIdx.x < nw) ? red[threadIdx.x] : 0.0f;
#pragma unroll
    for (int m = 8; m >= 1; m >>= 1) s += __shfl_xor(s, m, 16);
    if (threadIdx.x == 0) red[0] = s;
  }
  __syncthreads();
  float out = red[0];
  __syncthreads();
  return out;
}

__global__ __launch_bounds__(1024) void k_tanh(const float* __restrict__ w, float* __restrict__ o) {
  int i = blockIdx.x * 1024 + threadIdx.x;
  if (i < DET) o[i] = tanhf(w[i]);
}

// ---------------- prep (t=0 only) ----------------
__global__ __launch_bounds__(256) void k_prep(
    const float* __restrict__ isf, const float* __restrict__ pa, int t,
    const float* __restrict__ stoch_prev,
    const float* __restrict__ deter_prev, long deter_prev_stride,
    const float* __restrict__ init_stoch, const float* __restrict__ init_deter_row,
    float* __restrict__ stoch_in, float* __restrict__ deter_in, float* __restrict__ a_eff) {
  int r = blockIdx.x;
  float f = isf[r * T_STEPS + t];
  float omf = 1.0f - f;
  for (int c = threadIdx.x; c < SD; c += 256)
    stoch_in[r * SD + c] = stoch_prev[r * SD + c] * omf + init_stoch[r * SD + c] * f;
  for (int c = threadIdx.x; c < DET; c += 256)
    deter_in[r * DET + c] = deter_prev[(long)r * deter_prev_stride + c] * omf + init_deter_row[c] * f;
  if ((int)threadIdx.x < A_DIM) {
    float a = pa[(r * T_STEPS + t) * A_DIM + threadIdx.x];
    a = a * (1.0f / fmaxf(fabsf(a), 1.0f));
    a_eff[r * 8 + threadIdx.x] = a * omf;
  }
}

// ---------------- generic K-split GEMM: P[split][16][N] partials ----------------
struct GemmArgs {
  const float* A0; long sA0; int cA0;
  const float* A1; long sA1;
  const float* W; int N; int Ktot; int KS; int nsplit;
  float* P;
};

template <bool NT>
__global__ __launch_bounds__(256) void k_gemm(GemmArgs ga, GemmArgs gb) {
  const GemmArgs g = blockIdx.z ? gb : ga;
  if ((int)blockIdx.y >= g.nsplit) return;
  const int tid = threadIdx.x;
  const int c0 = blockIdx.x * 512 + tid * 2;
  const int k0 = (int)blockIdx.y * g.KS;
  __shared__ float in_s[16][64];
  float acc[16][2];
#pragma unroll
  for (int r = 0; r < 16; r++) { acc[r][0] = 0.f; acc[r][1] = 0.f; }
  for (int kb = 0; kb < g.KS; kb += 64) {
    const int kbase = k0 + kb;
#pragma unroll
    for (int j = 0; j < 4; j++) {
      int ii = tid + j * 256;
      int r = ii >> 6, kk = ii & 63;
      int k = kbase + kk;
      float v = 0.f;
      if (k < g.cA0) v = g.A0[(long)r * g.sA0 + k];
      else if (k < g.Ktot) v = g.A1[(long)r * g.sA1 + (k - g.cA0)];
      in_s[r][kk] = v;
    }
    __syncthreads();
    if (kbase + 64 <= g.Ktot) {
      const float* wp = g.W + (size_t)kbase * g.N + c0;
#pragma unroll 4
      for (int kk = 0; kk < 64; kk++) {
        f2v w = NT ? __builtin_nontemporal_load((const f2v*)wp) : *(const f2v*)wp;
        wp += g.N;
#pragma unroll
        for (int r = 0; r < 16; r++) {
          float iv = in_s[r][kk];
          acc[r][0] += iv * w[0]; acc[r][1] += iv * w[1];
        }
      }
    } else {  // K tail (img1: Ktot=1030)
#pragma unroll 4
      for (int kk = 0; kk < 64; kk++) {
        int krow = kbase + kk; if (krow >= g.Ktot) krow = g.Ktot - 1;
        const f2v w = *(const f2v*)(g.W + (size_t)krow * g.N + c0);
#pragma unroll
        for (int r = 0; r < 16; r++) {
          float iv = in_s[r][kk];
          acc[r][0] += iv * w[0]; acc[r][1] += iv * w[1];
        }
      }
    }
    __syncthreads();
  }
#pragma unroll
  for (int r = 0; r < 16; r++)
    *(f2v*)(g.P + ((size_t)blockIdx.y * 16 + r) * g.N + c0) = f2v{acc[r][0], acc[r][1]};
}

// ---------------- obs-embed precompute: OE[m] = e[m] @ Wo[0:E]  (m = b*T+t) ----------
// 64x64 tile, 4x4 micro, 256 threads, grid (16,16). Writes out[m*8192+5120+c].
__global__ __launch_bounds__(256) void k_pre(const float* __restrict__ A,
                                             const float* __restrict__ Bw,
                                             float* __restrict__ ob) {
  __shared__ float As[32][68];
  __shared__ float Bs[32][68];
  const int tid = threadIdx.x;
  const int tx = tid & 15, ty = tid >> 4;
  const int row0 = blockIdx.y * 64, col0 = blockIdx.x * 64;
  const int ar = tid >> 2, ak = (tid & 3) * 8;
  const int bk = tid >> 4, bc = (tid & 15) * 4;
  float acc[4][4] = {};
  const float* ap = A + (size_t)(row0 + ar) * E_DIM + ak;
  const float* bp = Bw + (size_t)bk * HID + col0 + bc;
  for (int k0 = 0; k0 < E_DIM; k0 += 32) {
    float4 a0 = *(const float4*)(ap + k0);
    float4 a1 = *(const float4*)(ap + k0 + 4);
    float4 b0 = *(const float4*)(bp + (size_t)k0 * HID);
    float4 b1 = *(const float4*)(bp + (size_t)(k0 + 16) * HID);
    __syncthreads();
    As[ak + 0][ar] = a0.x; As[ak + 1][ar] = a0.y; As[ak + 2][ar] = a0.z; As[ak + 3][ar] = a0.w;
    As[ak + 4][ar] = a1.x; As[ak + 5][ar] = a1.y; As[ak + 6][ar] = a1.z; As[ak + 7][ar] = a1.w;
    *(float4*)&Bs[bk][bc] = b0;
    *(float4*)&Bs[bk + 16][bc] = b1;
    __syncthreads();
#pragma unroll
    for (int kk = 0; kk < 32; kk++) {
      float4 av = *(const float4*)&As[kk][ty * 4];
      float4 bv = *(const float4*)&Bs[kk][tx * 4];
      acc[0][0] += av.x * bv.x; acc[0][1] += av.x * bv.y; acc[0][2] += av.x * bv.z; acc[0][3] += av.x * bv.w;
      acc[1][0] += av.y * bv.x; acc[1][1] += av.y * bv.y; acc[1][2] += av.y * bv.z; acc[1][3] += av.y * bv.w;
      acc[2][0] += av.z * bv.x; acc[2][1] += av.z * bv.y; acc[2][2] += av.z * bv.z; acc[2][3] += av.z * bv.w;
      acc[3][0] += av.w * bv.x; acc[3][1] += av.w * bv.y; acc[3][2] += av.w * bv.z; acc[3][3] += av.w * bv.w;
    }
  }
#pragma unroll
  for (int i = 0; i < 4; i++)
#pragma unroll
    for (int j = 0; j < 4; j++)
      ob[(size_t)(row0 + ty * 4 + i) * OUT_C + col0 + tx * 4 + j] = acc[i][j];
}

// ---------------- GRU stage-1 reduce: sum splits + (sum, sumsq) per chunk ----------
__global__ __launch_bounds__(256) void k_red(const float* __restrict__ P, int nP,
                                             float* __restrict__ S,
                                             float* __restrict__ red_s, float* __restrict__ red_q) {
  int chunk = blockIdx.x, r = blockIdx.y;
  int c = chunk * 1024 + threadIdx.x * 4;
  float4 s = {0, 0, 0, 0};
  for (int ks = 0; ks < nP; ks++) {
    float4 v = *(const float4*)(P + ((size_t)ks * 16 + r) * (3 * DET) + c);
    s.x += v.x; s.y += v.y; s.z += v.z; s.w += v.w;
  }
  *(float4*)(S + (size_t)r * (3 * DET) + c) = s;
  float sx = (s.x + s.y) + (s.z + s.w);
  float sq = (s.x * s.x + s.y * s.y) + (s.z * s.z + s.w * s.w);
  __shared__ float rbuf[8];
#pragma unroll
  for (int m = 32; m >= 1; m >>= 1) { sx += __shfl_xor(sx, m, 64); sq += __shfl_xor(sq, m, 64); }
  int wid = threadIdx.x >> 6;
  if ((threadIdx.x & 63) == 0) { rbuf[wid] = sx; rbuf[4 + wid] = sq; }
  __syncthreads();
  if (threadIdx.x == 0) {
    red_s[r * 12 + chunk] = (rbuf[0] + rbuf[1]) + (rbuf[2] + rbuf[3]);
    red_q[r * 12 + chunk] = (rbuf[4] + rbuf[5]) + (rbuf[6] + rbuf[7]);
  }
}

// ---------------- GRU stage-2: LN + gates + deter_new + next-step deter blend ----------
__global__ __launch_bounds__(1024) void k_gru_gate(
    const float* __restrict__ S, const float* __restrict__ red_s, const float* __restrict__ red_q,
    const float* __restrict__ g, const float* __restrict__ b,
    float* __restrict__ deter_in, float* __restrict__ deter_new,
    float* __restrict__ out_deter, const float* __restrict__ isf, int t,
    const float* __restrict__ init_deter) {
  int r = blockIdx.x;
  __shared__ float mv[2];
  if (threadIdx.x == 0) {
    float s = 0.f, q = 0.f;
    for (int k2 = 0; k2 < 12; k2++) { s += red_s[r * 12 + k2]; q += red_q[r * 12 + k2]; }
    float m = s * (1.0f / (float)(3 * DET));
    float var = q * (1.0f / (float)(3 * DET)) - m * m;
    mv[0] = m; mv[1] = 1.0f / sqrtf(var + 1e-3f);
  }
  __syncthreads();
  float m = mv[0], rs = mv[1];
  float ft = (t + 1 < T_STEPS) ? isf[r * T_STEPS + t + 1] : 0.0f;
  for (int j = threadIdx.x; j < DET; j += 1024) {
    float lr = (S[(size_t)r * (3 * DET) + j] - m) * rs * g[j] + b[j];
    float lc = (S[(size_t)r * (3 * DET) + j + DET] - m) * rs * g[j + DET] + b[j + DET];
    float lu = (S[(size_t)r * (3 * DET) + j + 2 * DET] - m) * rs * g[j + 2 * DET] + b[j + 2 * DET];
    float rr = 1.0f / (1.0f + expf(-lr));
    float cd = tanhf(rr * lc);
    float uu = 1.0f / (1.0f + expf(-(lu - 1.0f)));
    float dn = uu * cd + (1.0f - uu) * deter_in[r * DET + j];
    deter_new[r * DET + j] = dn;
    out_deter[(size_t)r * OUT_RSTRIDE + j] = dn;
    deter_in[r * DET + j] = dn * (1.0f - ft) + init_deter[j] * ft;
  }
}

// ---------------- batched finish: (optional add) + sum partials + LN + silu ----------
__global__ __launch_bounds__(1024) void k_fin2(
    const float* __restrict__ Pa_, int nPa, const float* __restrict__ addA, long adsA,
    const float* __restrict__ gva, const float* __restrict__ bva, float* __restrict__ oa,
    const float* __restrict__ Pb_, int nPb, const float* __restrict__ addB, long adsB,
    const float* __restrict__ gvb, const float* __restrict__ bvb, float* __restrict__ ob) {
  int which = blockIdx.x >> 4, r = blockIdx.x & 15, c = threadIdx.x;
  const float* P = which ? Pb_ : Pa_;
  int nP = which ? nPb : nPa;
  const float* add = which ? addB : addA;
  long ads = which ? adsB : adsA;
  const float* gv = which ? gvb : gva;
  const float* bv = which ? bvb : bva;
  float* o = which ? ob : oa;
  __shared__ float red[18];
  float v = add ? add[(size_t)r * ads + c] : 0.0f;
  for (int ks = 0; ks < nP; ks++) v += P[((size_t)ks * 16 + r) * HID + c];
  float m = block_sum(v, red, 16) * (1.0f / (float)HID);
  float d = v - m;
  float var = block_sum(d * d, red, 16) * (1.0f / (float)HID);
  float rs = 1.0f / sqrtf(var + 1e-3f);
  float y = d * rs * gv[c] + bv[c];
  float s = 1.0f / (1.0f + expf(-y));
  o[r * HID + c] = y * s;
}

// ---------------- batched sample finish + next-step stoch/a blend ----------------
__global__ __launch_bounds__(1024) void k_samp(
    const float* __restrict__ P0, const float* __restrict__ bb0,
    const float* __restrict__ gum0, long gs0,
    float* __restrict__ st0, long ss0, float* __restrict__ lg0, long ls0,
    const float* __restrict__ P1, const float* __restrict__ bb1,
    const float* __restrict__ gum1, long gs1,
    float* __restrict__ st1, long ss1, float* __restrict__ lg1, long ls1,
    int nP,
    const float* __restrict__ isf, const float* __restrict__ pa, int t,
    float* __restrict__ stoch_in, float* __restrict__ a_eff,
    const float* __restrict__ init_stoch) {
  int which = blockIdx.x >> 4, r = blockIdx.x & 15, c = threadIdx.x;
  const float* P = which ? P1 : P0;
  const float* bbv = which ? bb1 : bb0;
  const float* gum = which ? gum1 : gum0;
  long gs = which ? gs1 : gs0;
  float* st = which ? st1 : st0;
  long ss = which ? ss1 : ss0;
  float* lg = which ? lg1 : lg0;
  long ls = which ? ls1 : ls0;
  float acc = bbv[c];
  for (int ks = 0; ks < nP; ks++) acc += P[((size_t)ks * 16 + r) * SD + c];
  int d = c & 31;
  float mx = acc;
#pragma unroll
  for (int m = 16; m >= 1; m >>= 1) mx = fmaxf(mx, __shfl_xor(mx, m, 32));
  float e = expf(acc - mx);
  float se = e;
#pragma unroll
  for (int m = 16; m >= 1; m >>= 1) se += __shfl_xor(se, m, 32);
  float p = 0.99f * (e / se) + 3.125e-4f;
  float y = gum ? (logf(p) + gum[(long)r * gs + c]) : p;
  float by = y; int bi = d;
#pragma unroll
  for (int m = 16; m >= 1; m >>= 1) {
    float oy = __shfl_xor(by, m, 32);
    int oi = __shfl_xor(bi, m, 32);
    if (oy > by || (oy == by && oi < bi)) { by = oy; bi = oi; }
  }
  float oh = (d == bi) ? 1.0f : 0.0f;
  float outv = (oh + p) - p;
  st[(long)r * ss + c] = outv;
  if (lg) lg[(long)r * ls + c] = acc;
  if (which && stoch_in) {
    float fn = (t + 1 < T_STEPS) ? isf[r * T_STEPS + t + 1] : 0.0f;
    stoch_in[r * SD + c] = outv * (1.0f - fn) + init_stoch[r * SD + c] * fn;
    if (c < A_DIM) {
      float a = (t + 1 < T_STEPS) ? pa[(r * T_STEPS + t + 1) * A_DIM + c] : 0.0f;
      a = a * (1.0f / fmaxf(fabsf(a), 1.0f));
      a_eff[r * 8 + c] = a * (1.0f - fn);
    }
  }
}

// ---------------- host ----------------
static inline GemmArgs mkargs(const float* A0, long sA0, int cA0,
                              const float* A1, long sA1,
                              const float* W, int N, int Ktot, int KS, int nsplit, float* P) {
  GemmArgs g; g.A0 = A0; g.sA0 = sA0; g.cA0 = cA0; g.A1 = A1; g.sA1 = sA1;
  g.W = W; g.N = N; g.Ktot = Ktot; g.KS = KS; g.nsplit = nsplit; g.P = P;
  return g;
}

extern "C" void kernel_launch(void* const* d_in, const int* in_sizes, int n_in,
                              void* d_out, int out_size, void* d_ws, size_t ws_size,
                              hipStream_t stream) {
  const float* embed  = (const float*)d_in[0];
  const float* pa     = (const float*)d_in[1];
  const float* isf    = (const float*)d_in[2];
  const float* gprior = (const float*)d_in[3];
  const float* gpost  = (const float*)d_in[4];
  const float* w_init = (const float*)d_in[5];
  const float* W1  = (const float*)d_in[6];
  const float* g1  = (const float*)d_in[7];
  const float* b1  = (const float*)d_in[8];
  const float* Wg  = (const float*)d_in[9];
  const float* gg  = (const float*)d_in[10];
  const float* bg  = (const float*)d_in[11];
  const float* W2a = (const float*)d_in[12];
  const float* g2  = (const float*)d_in[13];
  const float* b2  = (const float*)d_in[14];
  const float* W2b = (const float*)d_in[15];
  const float* bb2 = (const float*)d_in[16];
  const float* Wo  = (const float*)d_in[17];
  const float* go  = (const float*)d_in[18];
  const float* bo  = (const float*)d_in[19];
  const float* Wob = (const float*)d_in[20];
  const float* bbo = (const float*)d_in[21];
  float* out = (float*)d_out;
  float* ws  = (float*)d_ws;

  // workspace layout (floats)
  float* Pg    = ws;                         // 20*16*12288 = 3,932,160
  float* Sg    = Pg + 3932160;               // 16*12288    = 196,608
  float* red_s = Sg + 196608;                // 192
  float* red_q = red_s + 192;                // 192 (+pad)
  float* Pa    = red_s + 512;                // 32*16*1024 = 524,288
  float* Pb    = Pa + 524288;                // 524,288
  float* Ps0   = Pb + 524288;                // 16*16*1024 = 262,144
  float* Ps1   = Ps0 + 262144;               // 262,144
  float* Pimg1 = Pa;                         // alias (17*16*1024 = 278,528 <= 524,288)
  float* st_   = Ps1 + 262144;
  float* init_stoch = st_;                   // 16,384
  float* init_deter = st_ + 16384;           // 4,096
  float* stoch_in   = st_ + 20480;           // 16,384
  float* deter_in   = st_ + 36864;           // 65,536
  float* deter_new  = st_ + 102400;          // 65,536
  float* a_eff      = st_ + 167936;          // 128
  float* x          = st_ + 168064;          // 16,384
  float* h          = st_ + 184448;          // 16,384
  float* h2         = st_ + 200832;          // 16,384

  GemmArgs Z = mkargs(nullptr, 0, 0, nullptr, 0, nullptr, 1, 0, 64, 0, nullptr);

  // ---- obs-embed precompute: OE -> d_out post-logits slots (overwritten later) ----
  k_pre<<<dim3(16, 16), 256, 0, stream>>>(embed, Wo, out + 5120);

  // ---- init: init_deter = tanh(w_init); init_stoch = st_mode(prior_logits(init_deter))
  k_tanh<<<4, 1024, 0, stream>>>(w_init, init_deter);
  {
    GemmArgs g = mkargs(init_deter, 0, DET, nullptr, 0, W2a, HID, DET, 128, 32, Pa);
    k_gemm<true><<<dim3(2, 32, 1), 256, 0, stream>>>(g, Z);
  }
  k_fin2<<<16, 1024, 0, stream>>>(Pa, 32, nullptr, 0, g2, b2, h,
                                  Pa, 32, nullptr, 0, g2, b2, h);
  {
    GemmArgs g = mkargs(h, HID, HID, nullptr, 0, W2b, SD, HID, 64, 16, Ps0);
    k_gemm<true><<<dim3(2, 16, 1), 256, 0, stream>>>(g, Z);
  }
  k_samp<<<16, 1024, 0, stream>>>(Ps0, bb2, nullptr, 0, init_stoch, SD, nullptr, 0,
                                  Ps0, bb2, nullptr, 0, init_stoch, SD, nullptr, 0,
                                  16, isf, pa, -1, nullptr, nullptr, init_stoch);

  // ---- t=0 prep (f[:,0]==1 -> all init) ----
  k_prep<<<16, 256, 0, stream>>>(isf, pa, 0, init_stoch, init_deter, 0,
                                 init_stoch, init_deter, stoch_in, deter_in, a_eff);

  for (int t = 0; t < T_STEPS; t++) {
    {  // img1: concat(stoch,a)[1030] @ W1 -> 1024
      GemmArgs g = mkargs(stoch_in, SD, SD, a_eff, 8, W1, HID, SD + A_DIM, 64, 17, Pimg1);
      k_gemm<true><<<dim3(2, 17, 1), 256, 0, stream>>>(g, Z);
    }
    k_fin2<<<16, 1024, 0, stream>>>(Pimg1, 17, nullptr, 0, g1, b1, x,
                                    Pimg1, 17, nullptr, 0, g1, b1, x);
    {  // GRU: concat(x,deter_in)[5120] @ Wg -> 12288 (keep Wg L3-cacheable)
      GemmArgs g = mkargs(x, HID, HID, deter_in, DET, Wg, 3 * DET, HID + DET, 256, 20, Pg);
      k_gemm<false><<<dim3(24, 20, 1), 256, 0, stream>>>(g, Z);
    }
    k_red<<<dim3(12, 16), 256, 0, stream>>>(Pg, 20, Sg, red_s, red_q);
    k_gru_gate<<<16, 1024, 0, stream>>>(Sg, red_s, red_q, gg, bg, deter_in, deter_new,
                                        out + (size_t)t * OUT_C + 1024, isf, t, init_deter);
    {  // batched: prior img2a (4096->1024) || obs deter-part (4096->1024)
      GemmArgs gp = mkargs(deter_new, DET, DET, nullptr, 0, W2a, HID, DET, 128, 32, Pa);
      GemmArgs go_ = mkargs(deter_new, DET, DET, nullptr, 0, Wo + (size_t)E_DIM * HID,
                            HID, DET, 128, 32, Pb);
      k_gemm<true><<<dim3(2, 32, 2), 256, 0, stream>>>(gp, go_);
    }
    k_fin2<<<32, 1024, 0, stream>>>(Pa, 32, nullptr, 0, g2, b2, h,
                                    Pb, 32, out + (size_t)t * OUT_C + 5120, OUT_RSTRIDE,
                                    go, bo, h2);
    {  // batched sample GEMMs: h@W2b || h2@Wob
      GemmArgs gs0 = mkargs(h, HID, HID, nullptr, 0, W2b, SD, HID, 64, 16, Ps0);
      GemmArgs gs1 = mkargs(h2, HID, HID, nullptr, 0, Wob, SD, HID, 64, 16, Ps1);
      k_gemm<true><<<dim3(2, 16, 2), 256, 0, stream>>>(gs0, gs1);
    }
    k_samp<<<32, 1024, 0, stream>>>(
        Ps0, bb2, gprior + (size_t)t * SD, (long)T_STEPS * SD,
        out + (size_t)t * OUT_C + 6144, OUT_RSTRIDE,
        out + (size_t)t * OUT_C + 7168, OUT_RSTRIDE,
        Ps1, bbo, gpost + (size_t)t * SD, (long)T_STEPS * SD,
        out + (size_t)t * OUT_C + 0, OUT_RSTRIDE,
        out + (size_t)t * OUT_C + 5120, OUT_RSTRIDE,
        16, isf, pa, t, stoch_in, a_eff, init_stoch);
  }
}